// Round 13
// baseline (189.203 us; speedup 1.0000x reference)
//
#include <hip/hip_runtime.h>
#include <hip/hip_bf16.h>

#define B 4
#define N 1024
#define KNN 30
#define MM 8
#define HID 16
#define FD 320
#define OUTC 512
#define BNS 0.9999950000374997f   // 1/sqrt(1+1e-5)

typedef float f32x4 __attribute__((ext_vector_type(4)));
typedef short s16x8 __attribute__((ext_vector_type(8)));

// workspace float offsets
#define OFF_IDX  0        // 122880 ints
#define OFF_CVT  122880   // cvt bf16 512*320 -> 81920 float slots
#define OFF_K2T  204800   // k2t bf16 4*64*1024 -> 131072 float slots
#define OFF_FB   335872   // feats bf16 4096*320 -> 655360 float slots
#define OFF_SC   991232   // score: 4*4096*240 floats

// k1 LDS pool byte offsets (k1 branch | prep branch overlays at 0)
#define L_HIST 0          // uint[4][256]        4096
#define L_JS   4096       // int[4][30]          480
#define L_BPN  4576       // uint bp[4], int bn[4]  32
#define L_DIFF 4608       // float[4][30][12]    5760  (16-aligned)
#define L_NBR  10368      // float[4][30][12]    5760
#define L_CTR  16128      // float[4][9]         144
#define L_HWS  16272      // float[1792]         7168
#define L_OWS  23440      // float[512]          2048
#define L_OBS  25488      // float[32]           128
#define K1_LDS 25616      // prep tile[64][65] = 16640 overlays at 0

// ---------------- k1: prep-blocks + {knn radix + conv1 + scorenet} ----------
// x is already SoA per batch: x[b][c][n] -> coalesced distance loads.
__global__ void __launch_bounds__(256) k1(const float* __restrict__ x,
                                          const float* __restrict__ conv1_w,
                                          const float* __restrict__ conv1_b,
                                          const float* __restrict__ hw,
                                          const float* __restrict__ ow,
                                          const float* __restrict__ ob,
                                          const float* __restrict__ mats,
                                          const float* __restrict__ convt_w,
                                          int* __restrict__ idx,
                                          __hip_bfloat16* __restrict__ feats_bf,
                                          float* __restrict__ score,
                                          __hip_bfloat16* __restrict__ k2t_bf,
                                          __hip_bfloat16* __restrict__ cvt_bf,
                                          float* __restrict__ out) {
  __shared__ __align__(16) char pool[K1_LDS];
  int t = threadIdx.x;

  if (blockIdx.x >= 1024) {             // ---- prep branch ----
    int pb = blockIdx.x - 1024;
    if (pb < 64) {                       // k2t transpose via LDS tile
      float (*tile)[65] = (float(*)[65])pool;
      int l = pb >> 4, part = (pb >> 3) & 1, m = pb & 7;
      int tr = t >> 6, tc = t & 63;
      const float* src = mats + l * 65536 + (part * 64) * 512 + m * 64;
#pragma unroll
      for (int it = 0; it < 16; it++) { int c = it * 4 + tr; tile[c][tc] = src[c * 512 + tc]; }
      __syncthreads();
      __hip_bfloat16* dst = k2t_bf + l * 65536 + part * 512 + m * 64;
#pragma unroll
      for (int it = 0; it < 16; it++) { int o = it * 4 + tr; dst[o * 1024 + tc] = __float2bfloat16(tile[tc][o]); }
    } else {                             // cvt + out zero
      int id = (pb - 64) * 256 + t;      // 0..40959
#pragma unroll
      for (int q = 0; q < 4; q++) {
        int i = id + q * 40960;
        cvt_bf[i] = __float2bfloat16(convt_w[i]);
      }
      if (id < B * OUTC) out[id] = 0.f;
    }
    return;
  }

  // ---- k1 branch ----
  unsigned int* hist = (unsigned int*)(pool + L_HIST);
  int* js_l = (int*)(pool + L_JS);
  unsigned int* bp = (unsigned int*)(pool + L_BPN);
  int* bn = (int*)(pool + L_BPN + 16);
  float (*diff_s)[KNN][12] = (float(*)[KNN][12])(pool + L_DIFF);
  float (*nbr_s)[KNN][12] = (float(*)[KNN][12])(pool + L_NBR);
  float (*ctr_s)[9] = (float(*)[9])(pool + L_CTR);
  float* hws = (float*)(pool + L_HWS);
  float* ows = (float*)(pool + L_OWS);
  float* obs = (float*)(pool + L_OBS);

  int r = t >> 6, lane = t & 63;
  int row = blockIdx.x * 4 + r;
  int b = row >> 10;
  const float* xb = x + b * 9216;    // xb[c*1024 + j]

  for (int i = t; i < 1792; i += 256) hws[i] = hw[i];
  for (int i = t; i < 512; i += 256) ows[i] = ow[i];
  if (t < 32) obs[t] = ob[t];
  if (t < 36) { int rr = t / 9, c = t - rr * 9; ctr_s[rr][c] = xb[c * 1024 + ((blockIdx.x * 4 + rr) & 1023)]; }

  // ---- distances (sq on the fly; self exactly 0: identical fma chains) ----
  int jrow = row & 1023;
  float cx[9];
#pragma unroll
  for (int c = 0; c < 9; c++) cx[c] = xb[c * 1024 + jrow];
  float sqn = 0.f;
#pragma unroll
  for (int c = 0; c < 9; c++) sqn = fmaf(cx[c], cx[c], sqn);
  unsigned int key[16];
#pragma unroll
  for (int s = 0; s < 16; s++) {
    int j = s * 64 + lane;
    float dot = 0.f, sbj = 0.f;
#pragma unroll
    for (int c = 0; c < 9; c++) {
      float xjc = xb[c * 1024 + j];
      dot = fmaf(cx[c], xjc, dot);
      sbj = fmaf(xjc, xjc, sbj);
    }
    float v = 2.0f * dot - sqn - sbj;
    unsigned u = __float_as_uint(v);
    key[s] = u ^ ((unsigned)(((int)u) >> 31) | 0x80000000u);   // asc-sortable
  }
  // ---- exact top-30 radix select ----
  unsigned prefix = 0; int need = KNN;
  for (int p = 0; p < 4; p++) {
    int shift = 24 - 8 * p;
    for (int i = lane; i < 256; i += 64) hist[r * 256 + i] = 0;
    __syncthreads();
    unsigned himask = p ? (0xFFFFFFFFu << (shift + 8)) : 0u;
#pragma unroll
    for (int s = 0; s < 16; s++)
      if ((key[s] & himask) == prefix) atomicAdd(&hist[r * 256 + ((key[s] >> shift) & 255)], 1u);
    __syncthreads();
    int c0 = hist[r * 256 + 4 * lane], c1 = hist[r * 256 + 4 * lane + 1];
    int c2 = hist[r * 256 + 4 * lane + 2], c3 = hist[r * 256 + 4 * lane + 3];
    int lsum = c0 + c1 + c2 + c3, sfx = lsum;
#pragma unroll
    for (int ofs = 1; ofs < 64; ofs <<= 1) {
      int tt = __shfl_down(sfx, ofs, 64);
      if (lane + ofs < 64) sfx += tt;
    }
    int A3 = sfx - lsum, A2 = A3 + c3, A1 = A2 + c2, A0 = A1 + c1;
    if (A0 < need && need <= A0 + c0) { bp[r] = prefix | ((unsigned)(4 * lane + 0) << shift); bn[r] = need - A0; }
    if (A1 < need && need <= A1 + c1) { bp[r] = prefix | ((unsigned)(4 * lane + 1) << shift); bn[r] = need - A1; }
    if (A2 < need && need <= A2 + c2) { bp[r] = prefix | ((unsigned)(4 * lane + 2) << shift); bn[r] = need - A2; }
    if (A3 < need && need <= A3 + c3) { bp[r] = prefix | ((unsigned)(4 * lane + 3) << shift); bn[r] = need - A3; }
    __syncthreads();
    prefix = bp[r]; need = bn[r];
  }
  unsigned T = prefix;
  int* orow = idx + row * KNN;
  unsigned long long lowmask = (1ull << lane) - 1ull;
  int aboveBase = 0;                          // deterministic ballot emission
#pragma unroll
  for (int s = 0; s < 16; s++) {
    unsigned long long mA = __ballot(key[s] > T);
    if (key[s] > T) {
      int slot = aboveBase + __popcll(mA & lowmask);
      orow[slot] = s * 64 + lane;
      js_l[r * KNN + slot] = s * 64 + lane;
    }
    aboveBase += __popcll(mA);
  }
  int tieBase = 0;                            // ties ascending idx (JAX-stable)
  for (int s = 0; s < 16 && tieBase < need; s++) {
    unsigned long long mT = __ballot(key[s] == T);
    if (key[s] == T) {
      int rk = tieBase + __popcll(mT & lowmask);
      if (rk < need) {
        orow[aboveBase + rk] = s * 64 + lane;
        js_l[r * KNN + aboveBase + rk] = s * 64 + lane;
      }
    }
    tieBase += __popcll(mT);
  }
  __syncthreads();

  // ---- neighbor staging (exact nbr + diff) ----
  if (t < 120) {
    int rr = t / KNN, k = t - rr * KNN;
    int j = js_l[rr * KNN + k];
#pragma unroll
    for (int c = 0; c < 9; c++) {
      float nb = xb[c * 1024 + j];
      nbr_s[rr][k][c] = nb;
      diff_s[rr][k][c] = nb - ctr_s[rr][c];
    }
  }
  __syncthreads();

  // ---- conv1 + max_k (weights straight from global; L1-resident) ----
  {
    float wd[9];
#pragma unroll
    for (int c = 0; c < 9; c++) wd[c] = conv1_w[lane * 18 + c];
    float cd = 0.f;
#pragma unroll
    for (int c = 0; c < 9; c++) cd = fmaf(ctr_s[r][c], conv1_w[lane * 18 + 9 + c], cd);
    float best = -3.0e38f;
    for (int k = 0; k < KNN; k++) {
      const f32x4* dr = (const f32x4*)diff_s[r][k];
      f32x4 d0 = dr[0], d1 = dr[1], d2 = dr[2];
      float dd = 0.f;
      dd = fmaf(d0.x, wd[0], dd); dd = fmaf(d0.y, wd[1], dd);
      dd = fmaf(d0.z, wd[2], dd); dd = fmaf(d0.w, wd[3], dd);
      dd = fmaf(d1.x, wd[4], dd); dd = fmaf(d1.y, wd[5], dd);
      dd = fmaf(d1.z, wd[6], dd); dd = fmaf(d1.w, wd[7], dd);
      dd = fmaf(d2.x, wd[8], dd);
      best = fmaxf(best, dd);
    }
    float val = (best + cd + conv1_b[lane]) * BNS;
    feats_bf[row * FD + lane] = __float2bfloat16(fmaxf(val, 0.f));
  }

  // ---- scorenet flattened over (layer,item): 480 pairs, all 256 threads ----
  for (int i = t; i < 480; i += 256) {
    int l = i / 120;
    int rem = i - l * 120;
    int rr = rem / KNN, k = rem - rr * KNN;
    float xv[28];
    float d2 = 0.f;
#pragma unroll
    for (int c = 0; c < 9; c++) {
      float df = diff_s[rr][k][c];
      xv[c] = df; xv[9 + c] = nbr_s[rr][k][c]; xv[18 + c] = ctr_s[rr][c];
      d2 = fmaf(df, df, d2);
    }
    xv[27] = sqrtf(d2);
    float hid[HID];
#pragma unroll
    for (int h = 0; h < HID; h++) {
      float a = 0.f;
#pragma unroll
      for (int c = 0; c < 28; c++) a = fmaf(xv[c], hws[l * 448 + h * 28 + c], a);
      hid[h] = fmaxf(a * BNS, 0.f);
    }
    float lg[MM], mx = -3.0e38f;
#pragma unroll
    for (int m = 0; m < MM; m++) {
      float a = obs[l * 8 + m];
#pragma unroll
      for (int h = 0; h < HID; h++) a = fmaf(hid[h], ows[l * 128 + m * 16 + h], a);
      lg[m] = a; mx = fmaxf(mx, a);
    }
    float s = 0.f;
#pragma unroll
    for (int m = 0; m < MM; m++) { lg[m] = __expf(lg[m] - mx); s += lg[m]; }
    float inv = 1.0f / s;
    int rowr = blockIdx.x * 4 + rr;
    float* so = score + l * 983040 + (rowr * KNN + k) * 8;
    *(float4*)so = make_float4(lg[0] * inv, lg[1] * inv, lg[2] * inv, lg[3] * inv);
    *(float4*)(so + 4) = make_float4(lg[4] * inv, lg[5] * inv, lg[6] * inv, lg[7] * inv);
  }
}

// ---------------- layer: g + 8-wave K-split (H @ K2) MFMA; last folds final -
#define HSTR 1048   // Hs row stride bf16: 524 dw ≡ 12 mod 32 -> ~2-way (free)
__global__ void __launch_bounds__(512) k_layer2(const int* __restrict__ idx,
                                                const float* __restrict__ score,
                                                const __hip_bfloat16* __restrict__ k2t_bf,
                                                __hip_bfloat16* __restrict__ feats_bf,
                                                const __hip_bfloat16* __restrict__ cvt_bf,
                                                float* __restrict__ out,
                                                int l, int last) {
  int row0 = blockIdx.x * 16;
  int t = threadIdx.x;
  int b = row0 >> 10;
  __shared__ int js[16][KNN];
  __shared__ float ssum[16][8];
  __shared__ __align__(16) __hip_bfloat16 Hs[16][HSTR];
  __shared__ __align__(16) __hip_bfloat16 ftile[16][336];
  __shared__ float pacc[8][16][16];
  const float* sc_l = score + l * 983040;
  for (int i = t; i < 16 * KNN; i += 512) {
    int r = i / KNN, k = i - r * KNN;
    js[r][k] = (b << 10) + idx[(row0 + r) * KNN + k];
  }
  if (t < 128) {
    int r = t >> 3, m = t & 7;
    float a = 0.f;
    for (int k = 0; k < KNN; k++) a += sc_l[(row0 + r) * 240 + k * 8 + m];
    ssum[r][m] = a;
  }
  __syncthreads();
  int w = t >> 6, lane = t & 63;
#pragma unroll
  for (int rr = 0; rr < 2; rr++) {
    int r = w * 2 + rr;
    int row = row0 + r;
    const float4* srow = (const float4*)(sc_l + row * 240);
    float g[MM] = {};
#pragma unroll 6
    for (int k = 0; k < KNN; k++) {
      float fv = __bfloat162float(feats_bf[js[r][k] * FD + l * 64 + lane]);
      float4 s0 = srow[2 * k], s1 = srow[2 * k + 1];
      g[0] = fmaf(s0.x, fv, g[0]); g[1] = fmaf(s0.y, fv, g[1]);
      g[2] = fmaf(s0.z, fv, g[2]); g[3] = fmaf(s0.w, fv, g[3]);
      g[4] = fmaf(s1.x, fv, g[4]); g[5] = fmaf(s1.y, fv, g[5]);
      g[6] = fmaf(s1.z, fv, g[6]); g[7] = fmaf(s1.w, fv, g[7]);
    }
    float fn = __bfloat162float(feats_bf[row * FD + l * 64 + lane]);
#pragma unroll
    for (int m = 0; m < MM; m++) {
      Hs[r][m * 64 + lane] = __float2bfloat16(g[m] - ssum[r][m] * fn);
      Hs[r][512 + m * 64 + lane] = __float2bfloat16(g[m]);
    }
  }
  __syncthreads();
  if (last) {
    const short* Fs = (const short*)feats_bf;
    {
      int r = t >> 5, c8 = (t & 31) * 8;
      *(s16x8*)&ftile[r][c8] = *(const s16x8*)(Fs + (row0 + r) * FD + c8);
    }
    __syncthreads();
  }
  int lr = lane & 15, lk8 = (lane >> 4) * 8;
  {   // K-split GEMM: wave w -> col-tile w&3, K-half w>>2
    int ct = w & 3, kh = w >> 2;
    const short* Ks2 = (const short*)(k2t_bf + l * 65536);
    const short* brow = Ks2 + (ct * 16 + lr) * 1024 + kh * 512 + lk8;
    const short* arow = (const short*)&Hs[lr][kh * 512 + lk8];
    f32x4 acc = {0.f, 0.f, 0.f, 0.f};
#pragma unroll 8
    for (int kk = 0; kk < 16; kk++) {
      s16x8 a = *(const s16x8*)(arow + kk * 32);
      s16x8 bb = *(const s16x8*)(brow + kk * 32);
      acc = __builtin_amdgcn_mfma_f32_16x16x32_bf16(a, bb, acc, 0, 0, 0);
    }
#pragma unroll
    for (int i = 0; i < 4; i++)
      pacc[w][(lane >> 4) * 4 + i][lr] = acc[i];
  }
  __syncthreads();
  if (w < 4) {
#pragma unroll
    for (int i = 0; i < 4; i++) {
      int ri = (lane >> 4) * 4 + i;
      float val = fmaxf((pacc[w][ri][lr] + pacc[w + 4][ri][lr]) * BNS, 0.f);
      __hip_bfloat16 vb = __float2bfloat16(val);
      if (!last) {
        feats_bf[(row0 + ri) * FD + (l + 1) * 64 + w * 16 + lr] = vb;
      } else {
        ftile[ri][256 + w * 16 + lr] = vb;
      }
    }
  }
  if (last) {
    __syncthreads();
    const short* Ws = (const short*)cvt_bf;
#pragma unroll
    for (int tn = 0; tn < 4; tn++) {
      int nb = w * 64 + tn * 16;
      const short* brow = Ws + (nb + lr) * FD + lk8;
      const short* arow = (const short*)&ftile[lr][lk8];
      f32x4 acc = {0.f, 0.f, 0.f, 0.f};
#pragma unroll
      for (int kk = 0; kk < 10; kk++) {
        s16x8 a = *(const s16x8*)(arow + kk * 32);
        s16x8 bb = *(const s16x8*)(brow + kk * 32);
        acc = __builtin_amdgcn_mfma_f32_16x16x32_bf16(a, bb, acc, 0, 0, 0);
      }
      float mx = fmaxf(fmaxf(acc[0], acc[1]), fmaxf(acc[2], acc[3]));
      mx = fmaxf(mx, __shfl_xor(mx, 16, 64));
      mx = fmaxf(mx, __shfl_xor(mx, 32, 64));
      if ((lane >> 4) == 0) {
        float val = fmaxf(mx * BNS, 0.f);
        atomicMax((unsigned int*)out + b * OUTC + nb + lr, __float_as_uint(val));
      }
    }
  }
}

extern "C" void kernel_launch(void* const* d_in, const int* in_sizes, int n_in,
                              void* d_out, int out_size, void* d_ws, size_t ws_size,
                              hipStream_t stream) {
  const float* x       = (const float*)d_in[0];
  const float* conv1_w = (const float*)d_in[3];
  const float* conv1_b = (const float*)d_in[4];
  const float* sn_hw   = (const float*)d_in[5];
  const float* sn_ow   = (const float*)d_in[6];
  const float* sn_ob   = (const float*)d_in[7];
  const float* mats    = (const float*)d_in[8];
  const float* convt_w = (const float*)d_in[9];
  float* out = (float*)d_out;

  float* wsp = (float*)d_ws;
  int* idx    = (int*)(wsp + OFF_IDX);
  __hip_bfloat16* cvt_bf = (__hip_bfloat16*)(wsp + OFF_CVT);
  __hip_bfloat16* k2t_bf = (__hip_bfloat16*)(wsp + OFF_K2T);
  __hip_bfloat16* feats_bf = (__hip_bfloat16*)(wsp + OFF_FB);
  float* score = wsp + OFF_SC;

  k1<<<1248, 256, 0, stream>>>(x, conv1_w, conv1_b, sn_hw, sn_ow, sn_ob,
                               mats, convt_w, idx, feats_bf, score,
                               k2t_bf, cvt_bf, out);
  for (int l = 0; l < 4; l++) {
    k_layer2<<<256, 512, 0, stream>>>(idx, score, k2t_bf, feats_bf,
                                      cvt_bf, out, l, l == 3 ? 1 : 0);
  }
}

// Round 15
// 183.028 us; speedup vs baseline: 1.0337x; 1.0337x over previous
//
#include <hip/hip_runtime.h>
#include <hip/hip_bf16.h>

#define B 4
#define N 1024
#define KNN 30
#define MM 8
#define HID 16
#define FD 320
#define OUTC 512
#define BNS 0.9999950000374997f   // 1/sqrt(1+1e-5)

typedef float f32x4 __attribute__((ext_vector_type(4)));
typedef short s16x8 __attribute__((ext_vector_type(8)));

// workspace float offsets
#define OFF_IDX  0        // 122880 ints
#define OFF_CVT  122880   // cvt bf16 512*320 -> 81920 float slots
#define OFF_K2T  204800   // k2t bf16 4*64*1024 -> 131072 float slots
#define OFF_FB   335872   // feats bf16 4096*320 -> 655360 float slots
#define OFF_SC   991232   // score: 4*4096*240 floats
#define OFF_SSUM 4923392  // ssum: 4*4096*8 floats

// k1 LDS pool byte offsets. hist (16KB) is dead after radix -> pmax overlays.
#define L_HIST 0          // uint[4][256][4]     16384   | pmax[4][2][64] 2048
#define L_JS   16384      // int[4][30]          480
#define L_BPN  16864      // uint bp[4]; int bn[4]; int wAbv[4][2]; int wTie[4][2]  96
#define L_DIFF 16960      // float[4][30][12]    5760
#define L_NBR  22720      // float[4][30][12]    5760
#define L_CTR  28480      // float[4][9]         144
#define L_HWS  28624      // float[1792]         7168
#define L_OWS  35792      // float[512]          2048
#define L_OBS  37840      // float[32]           128
#define K1_LDS 37968      // prep tile[64][65]=16640 overlays at 0

// ---------------- k1: prep-blocks + {knn radix + conv1 + scorenet + ssum} ---
// x is already SoA per batch: x[b][c][n] -> coalesced distance loads.
__global__ void __launch_bounds__(512) k1(const float* __restrict__ x,
                                          const float* __restrict__ conv1_w,
                                          const float* __restrict__ conv1_b,
                                          const float* __restrict__ hw,
                                          const float* __restrict__ ow,
                                          const float* __restrict__ ob,
                                          const float* __restrict__ mats,
                                          const float* __restrict__ convt_w,
                                          int* __restrict__ idx,
                                          __hip_bfloat16* __restrict__ feats_bf,
                                          float* __restrict__ score,
                                          float* __restrict__ ssum_g,
                                          __hip_bfloat16* __restrict__ k2t_bf,
                                          __hip_bfloat16* __restrict__ cvt_bf,
                                          float* __restrict__ out) {
  __shared__ __align__(16) char pool[K1_LDS];
  int t = threadIdx.x;

  if (blockIdx.x >= 1024) {             // ---- prep branch ----
    int pb = blockIdx.x - 1024;
    if (pb < 64) {                       // k2t transpose via LDS tile
      float (*tile)[65] = (float(*)[65])pool;
      int l = pb >> 4, part = (pb >> 3) & 1, m = pb & 7;
      int tr = t >> 6, tc = t & 63;      // tr 0..7
      const float* src = mats + l * 65536 + (part * 64) * 512 + m * 64;
#pragma unroll
      for (int it = 0; it < 8; it++) { int c = it * 8 + tr; tile[c][tc] = src[c * 512 + tc]; }
      __syncthreads();
      __hip_bfloat16* dst = k2t_bf + l * 65536 + part * 512 + m * 64;
#pragma unroll
      for (int it = 0; it < 8; it++) { int o = it * 8 + tr; dst[o * 1024 + tc] = __float2bfloat16(tile[tc][o]); }
    } else {                             // cvt + out zero
      int id = (pb - 64) * 512 + t;      // 0..81919
#pragma unroll
      for (int q = 0; q < 2; q++) {
        int i = id + q * 81920;
        cvt_bf[i] = __float2bfloat16(convt_w[i]);
      }
      if (id < B * OUTC) out[id] = 0.f;
    }
    return;
  }

  // ---- k1 branch: 4 rows, 2 waves per row ----
  unsigned int* hist = (unsigned int*)(pool + L_HIST);   // [r][digit][sub4]
  float (*pmax)[2][64] = (float(*)[2][64])(pool + L_HIST);  // overlays hist
  int* js_l = (int*)(pool + L_JS);
  unsigned int* bp = (unsigned int*)(pool + L_BPN);
  int* bn = (int*)(pool + L_BPN + 16);
  int* wAbv = (int*)(pool + L_BPN + 32);   // [r][half]
  int* wTie = (int*)(pool + L_BPN + 64);   // [r][half]
  float (*diff_s)[KNN][12] = (float(*)[KNN][12])(pool + L_DIFF);
  float (*nbr_s)[KNN][12] = (float(*)[KNN][12])(pool + L_NBR);
  float (*ctr_s)[9] = (float(*)[9])(pool + L_CTR);
  float* hws = (float*)(pool + L_HWS);
  float* ows = (float*)(pool + L_OWS);
  float* obs = (float*)(pool + L_OBS);

  int w = t >> 6, lane = t & 63;
  int r = w & 3, half = w >> 2;        // wave pair (r, half)
  int row = blockIdx.x * 4 + r;
  int b = row >> 10;
  const float* xb = x + b * 9216;      // xb[c*1024 + j]

  for (int i = t; i < 1792; i += 512) hws[i] = hw[i];
  if (t < 512) ows[t] = ow[t];
  if (t < 32) obs[t] = ob[t];
  if (t < 36) { int rr = t / 9, c = t - rr * 9; ctr_s[rr][c] = xb[c * 1024 + ((blockIdx.x * 4 + rr) & 1023)]; }

  // ---- distances: 8 segments per wave (sq on the fly; self exactly 0) ----
  int jrow = row & 1023;
  float cx[9];
#pragma unroll
  for (int c = 0; c < 9; c++) cx[c] = xb[c * 1024 + jrow];
  float sqn = 0.f;
#pragma unroll
  for (int c = 0; c < 9; c++) sqn = fmaf(cx[c], cx[c], sqn);
  unsigned int key[8];
#pragma unroll
  for (int s = 0; s < 8; s++) {
    int j = (half * 8 + s) * 64 + lane;
    float dot = 0.f, sbj = 0.f;
#pragma unroll
    for (int c = 0; c < 9; c++) {
      float xjc = xb[c * 1024 + j];
      dot = fmaf(cx[c], xjc, dot);
      sbj = fmaf(xjc, xjc, sbj);
    }
    float v = 2.0f * dot - sqn - sbj;
    unsigned u = __float_as_uint(v);
    key[s] = u ^ ((unsigned)(((int)u) >> 31) | 0x80000000u);   // asc-sortable
  }
  // ---- exact top-30 radix select (shared hist, 4-way sub-bucketed) ----
  unsigned prefix = 0; int need = KNN;
  int sub = t & 3;
  for (int p = 0; p < 4; p++) {
    int shift = 24 - 8 * p;
    for (int i = t; i < 4096; i += 512) hist[i] = 0;
    __syncthreads();
    unsigned himask = p ? (0xFFFFFFFFu << (shift + 8)) : 0u;
#pragma unroll
    for (int s = 0; s < 8; s++)
      if ((key[s] & himask) == prefix)
        atomicAdd(&hist[((r * 256 + ((key[s] >> shift) & 255)) << 2) | sub], 1u);
    __syncthreads();
    if (half == 0) {     // one wave per row scans
      int c0 = 0, c1 = 0, c2 = 0, c3 = 0;
#pragma unroll
      for (int q = 0; q < 4; q++) {
        c0 += hist[((r * 256 + 4 * lane + 0) << 2) | q];
        c1 += hist[((r * 256 + 4 * lane + 1) << 2) | q];
        c2 += hist[((r * 256 + 4 * lane + 2) << 2) | q];
        c3 += hist[((r * 256 + 4 * lane + 3) << 2) | q];
      }
      int lsum = c0 + c1 + c2 + c3, sfx = lsum;
#pragma unroll
      for (int ofs = 1; ofs < 64; ofs <<= 1) {
        int tt = __shfl_down(sfx, ofs, 64);
        if (lane + ofs < 64) sfx += tt;
      }
      int A3 = sfx - lsum, A2 = A3 + c3, A1 = A2 + c2, A0 = A1 + c1;
      if (A0 < need && need <= A0 + c0) { bp[r] = prefix | ((unsigned)(4 * lane + 0) << shift); bn[r] = need - A0; }
      if (A1 < need && need <= A1 + c1) { bp[r] = prefix | ((unsigned)(4 * lane + 1) << shift); bn[r] = need - A1; }
      if (A2 < need && need <= A2 + c2) { bp[r] = prefix | ((unsigned)(4 * lane + 2) << shift); bn[r] = need - A2; }
      if (A3 < need && need <= A3 + c3) { bp[r] = prefix | ((unsigned)(4 * lane + 3) << shift); bn[r] = need - A3; }
    }
    __syncthreads();
    prefix = bp[r]; need = bn[r];
  }
  unsigned T = prefix;
  // per-wave above/tie counts for deterministic two-phase emission
  {
    int myA = 0, myT = 0;
#pragma unroll
    for (int s = 0; s < 8; s++) {
      myA += __popcll(__ballot(key[s] > T));
      myT += __popcll(__ballot(key[s] == T));
    }
    if (lane == 0) { wAbv[r * 2 + half] = myA; wTie[r * 2 + half] = myT; }
  }
  __syncthreads();
  int* orow = idx + row * KNN;
  unsigned long long lowmask = (1ull << lane) - 1ull;
  int aboveTotal = KNN - need;
  {
    int base = half ? wAbv[r * 2] : 0;           // wave0's j's all < wave1's
#pragma unroll
    for (int s = 0; s < 8; s++) {
      unsigned long long mA = __ballot(key[s] > T);
      if (key[s] > T) {
        int slot = base + __popcll(mA & lowmask);
        orow[slot] = (half * 8 + s) * 64 + lane;
        js_l[r * KNN + slot] = (half * 8 + s) * 64 + lane;
      }
      base += __popcll(mA);
    }
    int tieBase = half ? wTie[r * 2] : 0;        // j-ascending tie subset
    for (int s = 0; s < 8 && tieBase < need; s++) {
      unsigned long long mT = __ballot(key[s] == T);
      if (key[s] == T) {
        int rk = tieBase + __popcll(mT & lowmask);
        if (rk < need) {
          orow[aboveTotal + rk] = (half * 8 + s) * 64 + lane;
          js_l[r * KNN + aboveTotal + rk] = (half * 8 + s) * 64 + lane;
        }
      }
      tieBase += __popcll(mT);
    }
  }
  __syncthreads();

  // ---- neighbor staging (exact nbr + diff) ----
  if (t < 120) {
    int rr = t / KNN, k = t - rr * KNN;
    int j = js_l[rr * KNN + k];
#pragma unroll
    for (int c = 0; c < 9; c++) {
      float nb = xb[c * 1024 + j];
      nbr_s[rr][k][c] = nb;
      diff_s[rr][k][c] = nb - ctr_s[rr][c];
    }
  }
  __syncthreads();

  // ---- conv1 + max_k split across wave pair (fmax exactly associative) ----
  {
    float wd[9];
#pragma unroll
    for (int c = 0; c < 9; c++) wd[c] = conv1_w[lane * 18 + c];
    float best = -3.0e38f;
    int k0 = half * 15, k1e = k0 + 15;
    for (int k = k0; k < k1e; k++) {
      const f32x4* dr = (const f32x4*)diff_s[r][k];
      f32x4 d0 = dr[0], d1 = dr[1], d2 = dr[2];
      float dd = 0.f;
      dd = fmaf(d0.x, wd[0], dd); dd = fmaf(d0.y, wd[1], dd);
      dd = fmaf(d0.z, wd[2], dd); dd = fmaf(d0.w, wd[3], dd);
      dd = fmaf(d1.x, wd[4], dd); dd = fmaf(d1.y, wd[5], dd);
      dd = fmaf(d1.z, wd[6], dd); dd = fmaf(d1.w, wd[7], dd);
      dd = fmaf(d2.x, wd[8], dd);
      best = fmaxf(best, dd);
    }
    pmax[r][half][lane] = best;
    __syncthreads();
    if (half == 0) {
      float cd = 0.f;
#pragma unroll
      for (int c = 0; c < 9; c++) cd = fmaf(ctr_s[r][c], conv1_w[lane * 18 + 9 + c], cd);
      float bestAll = fmaxf(pmax[r][0][lane], pmax[r][1][lane]);
      float val = (bestAll + cd + conv1_b[lane]) * BNS;
      feats_bf[row * FD + lane] = __float2bfloat16(fmaxf(val, 0.f));
    }
  }

  // ---- scorenet flattened over (layer,item): 480 pairs, 512 threads ----
  if (t < 480) {
    int l = t / 120;
    int rem = t - l * 120;
    int rr = rem / KNN, k = rem - rr * KNN;
    float xv[28];
    float d2 = 0.f;
#pragma unroll
    for (int c = 0; c < 9; c++) {
      float df = diff_s[rr][k][c];
      xv[c] = df; xv[9 + c] = nbr_s[rr][k][c]; xv[18 + c] = ctr_s[rr][c];
      d2 = fmaf(df, df, d2);
    }
    xv[27] = sqrtf(d2);
    float hid[HID];
#pragma unroll
    for (int h = 0; h < HID; h++) {
      float a = 0.f;
#pragma unroll
      for (int c = 0; c < 28; c++) a = fmaf(xv[c], hws[l * 448 + h * 28 + c], a);
      hid[h] = fmaxf(a * BNS, 0.f);
    }
    float lg[MM], mx = -3.0e38f;
#pragma unroll
    for (int m = 0; m < MM; m++) {
      float a = obs[l * 8 + m];
#pragma unroll
      for (int h = 0; h < HID; h++) a = fmaf(hid[h], ows[l * 128 + m * 16 + h], a);
      lg[m] = a; mx = fmaxf(mx, a);
    }
    float s = 0.f;
#pragma unroll
    for (int m = 0; m < MM; m++) { lg[m] = __expf(lg[m] - mx); s += lg[m]; }
    float inv = 1.0f / s;
    int rowr = blockIdx.x * 4 + rr;
    float* so = score + l * 983040 + (rowr * KNN + k) * 8;
    *(float4*)so = make_float4(lg[0] * inv, lg[1] * inv, lg[2] * inv, lg[3] * inv);
    *(float4*)(so + 4) = make_float4(lg[4] * inv, lg[5] * inv, lg[6] * inv, lg[7] * inv);
  }
  __syncthreads();

  // ---- ssum (once for all 4 layers; k-ascending chain, L2-hot readback) ----
  if (t < 128) {
    int l = t >> 5, rr = (t >> 3) & 3, m = t & 7;
    int rowr = blockIdx.x * 4 + rr;
    const float* sl = score + l * 983040 + rowr * 240 + m;
    float a = 0.f;
    for (int k = 0; k < KNN; k++) a += sl[k * 8];
    ssum_g[l * 32768 + rowr * 8 + m] = a;
  }
}

// ---------------- layer: g + 8-wave K-split (H @ K2) MFMA; last folds final -
#define HSTR 1048   // Hs row stride bf16: 524 dw ≡ 12 mod 32 -> ~2-way (free)
__global__ void __launch_bounds__(512) k_layer2(const int* __restrict__ idx,
                                                const float* __restrict__ score,
                                                const float* __restrict__ ssum_g,
                                                const __hip_bfloat16* __restrict__ k2t_bf,
                                                __hip_bfloat16* __restrict__ feats_bf,
                                                const __hip_bfloat16* __restrict__ cvt_bf,
                                                float* __restrict__ out,
                                                int l, int last) {
  int row0 = blockIdx.x * 16;
  int t = threadIdx.x;
  int b = row0 >> 10;
  __shared__ int js[16][KNN];
  __shared__ float ssum[16][8];
  __shared__ __align__(16) __hip_bfloat16 Hs[16][HSTR];
  __shared__ __align__(16) __hip_bfloat16 ftile[16][336];
  __shared__ float pacc[8][16][16];
  const float* sc_l = score + l * 983040;
  for (int i = t; i < 16 * KNN; i += 512) {
    int r = i / KNN, k = i - r * KNN;
    js[r][k] = (b << 10) + idx[(row0 + r) * KNN + k];
  }
  if (t < 128) ssum[t >> 3][t & 7] = ssum_g[l * 32768 + (row0 + (t >> 3)) * 8 + (t & 7)];
  __syncthreads();
  int w = t >> 6, lane = t & 63;
#pragma unroll
  for (int rr = 0; rr < 2; rr++) {
    int r = w * 2 + rr;
    int row = row0 + r;
    const float4* srow = (const float4*)(sc_l + row * 240);
    float g[MM] = {};
#pragma unroll 6
    for (int k = 0; k < KNN; k++) {
      float fv = __bfloat162float(feats_bf[js[r][k] * FD + l * 64 + lane]);
      float4 s0 = srow[2 * k], s1 = srow[2 * k + 1];
      g[0] = fmaf(s0.x, fv, g[0]); g[1] = fmaf(s0.y, fv, g[1]);
      g[2] = fmaf(s0.z, fv, g[2]); g[3] = fmaf(s0.w, fv, g[3]);
      g[4] = fmaf(s1.x, fv, g[4]); g[5] = fmaf(s1.y, fv, g[5]);
      g[6] = fmaf(s1.z, fv, g[6]); g[7] = fmaf(s1.w, fv, g[7]);
    }
    float fn = __bfloat162float(feats_bf[row * FD + l * 64 + lane]);
#pragma unroll
    for (int m = 0; m < MM; m++) {
      Hs[r][m * 64 + lane] = __float2bfloat16(g[m] - ssum[r][m] * fn);
      Hs[r][512 + m * 64 + lane] = __float2bfloat16(g[m]);
    }
  }
  __syncthreads();
  if (last) {
    const short* Fs = (const short*)feats_bf;
    {
      int r = t >> 5, c8 = (t & 31) * 8;
      *(s16x8*)&ftile[r][c8] = *(const s16x8*)(Fs + (row0 + r) * FD + c8);
    }
    __syncthreads();
  }
  int lr = lane & 15, lk8 = (lane >> 4) * 8;
  {   // K-split GEMM: wave w -> col-tile w&3, K-half w>>2
    int ct = w & 3, kh = w >> 2;
    const short* Ks2 = (const short*)(k2t_bf + l * 65536);
    const short* brow = Ks2 + (ct * 16 + lr) * 1024 + kh * 512 + lk8;
    const short* arow = (const short*)&Hs[lr][kh * 512 + lk8];
    f32x4 acc = {0.f, 0.f, 0.f, 0.f};
#pragma unroll 8
    for (int kk = 0; kk < 16; kk++) {
      s16x8 a = *(const s16x8*)(arow + kk * 32);
      s16x8 bb = *(const s16x8*)(brow + kk * 32);
      acc = __builtin_amdgcn_mfma_f32_16x16x32_bf16(a, bb, acc, 0, 0, 0);
    }
#pragma unroll
    for (int i = 0; i < 4; i++)
      pacc[w][(lane >> 4) * 4 + i][lr] = acc[i];
  }
  __syncthreads();
  if (w < 4) {
#pragma unroll
    for (int i = 0; i < 4; i++) {
      int ri = (lane >> 4) * 4 + i;
      float val = fmaxf((pacc[w][ri][lr] + pacc[w + 4][ri][lr]) * BNS, 0.f);
      __hip_bfloat16 vb = __float2bfloat16(val);
      if (!last) {
        feats_bf[(row0 + ri) * FD + (l + 1) * 64 + w * 16 + lr] = vb;
      } else {
        ftile[ri][256 + w * 16 + lr] = vb;
      }
    }
  }
  if (last) {
    __syncthreads();
    const short* Ws = (const short*)cvt_bf;
#pragma unroll
    for (int tn = 0; tn < 4; tn++) {
      int nb = w * 64 + tn * 16;
      const short* brow = Ws + (nb + lr) * FD + lk8;
      const short* arow = (const short*)&ftile[lr][lk8];
      f32x4 acc = {0.f, 0.f, 0.f, 0.f};
#pragma unroll
      for (int kk = 0; kk < 10; kk++) {
        s16x8 a = *(const s16x8*)(arow + kk * 32);
        s16x8 bb = *(const s16x8*)(brow + kk * 32);
        acc = __builtin_amdgcn_mfma_f32_16x16x32_bf16(a, bb, acc, 0, 0, 0);
      }
      float mx = fmaxf(fmaxf(acc[0], acc[1]), fmaxf(acc[2], acc[3]));
      mx = fmaxf(mx, __shfl_xor(mx, 16, 64));
      mx = fmaxf(mx, __shfl_xor(mx, 32, 64));
      if ((lane >> 4) == 0) {
        float val = fmaxf(mx * BNS, 0.f);
        atomicMax((unsigned int*)out + b * OUTC + nb + lr, __float_as_uint(val));
      }
    }
  }
}

extern "C" void kernel_launch(void* const* d_in, const int* in_sizes, int n_in,
                              void* d_out, int out_size, void* d_ws, size_t ws_size,
                              hipStream_t stream) {
  const float* x       = (const float*)d_in[0];
  const float* conv1_w = (const float*)d_in[3];
  const float* conv1_b = (const float*)d_in[4];
  const float* sn_hw   = (const float*)d_in[5];
  const float* sn_ow   = (const float*)d_in[6];
  const float* sn_ob   = (const float*)d_in[7];
  const float* mats    = (const float*)d_in[8];
  const float* convt_w = (const float*)d_in[9];
  float* out = (float*)d_out;

  float* wsp = (float*)d_ws;
  int* idx    = (int*)(wsp + OFF_IDX);
  __hip_bfloat16* cvt_bf = (__hip_bfloat16*)(wsp + OFF_CVT);
  __hip_bfloat16* k2t_bf = (__hip_bfloat16*)(wsp + OFF_K2T);
  __hip_bfloat16* feats_bf = (__hip_bfloat16*)(wsp + OFF_FB);
  float* score = wsp + OFF_SC;
  float* ssum_g = wsp + OFF_SSUM;

  k1<<<1248, 512, 0, stream>>>(x, conv1_w, conv1_b, sn_hw, sn_ow, sn_ob,
                               mats, convt_w, idx, feats_bf, score, ssum_g,
                               k2t_bf, cvt_bf, out);
  for (int l = 0; l < 4; l++) {
    k_layer2<<<256, 512, 0, stream>>>(idx, score, ssum_g, k2t_bf, feats_bf,
                                      cvt_bf, out, l, l == 3 ? 1 : 0);
  }
}